// Round 4
// baseline (637.641 us; speedup 1.0000x reference)
//
#include <hip/hip_runtime.h>

#define DI __device__ __forceinline__

typedef __attribute__((ext_vector_type(8))) unsigned short u16x8;
typedef __attribute__((ext_vector_type(8))) __bf16 bf16x8;
typedef __attribute__((ext_vector_type(4))) float f32x4;

constexpr int B_ = 2, S_ = 2048, H_ = 16, HID_ = 2048;
constexpr int QR = 1536, KVR = 512, DQK = 192;
constexpr int BS = B_ * S_;                 // 4096 rows
constexpr float SCALE = 0.07216878364870323f;   // 1/sqrt(192)
constexpr float QS = SCALE * 1.4426950408889634f; // fold log2e -> exp2 domain
constexpr int CKV_LD = 2176;                // merged qa|kva fp32 buffer ld

// HW bf16 convert (RTNE), 1 instr
DI unsigned short f2bf(float x){
  unsigned r;
  asm("v_cvt_pk_bf16_f32 %0, %1, %2" : "=v"(r) : "v"(x), "v"(x));
  return (unsigned short)r;
}
DI float bf2f(unsigned short h){
  return __builtin_bit_cast(float, ((unsigned)h) << 16);
}
DI f32x4 mfma16(u16x8 a, u16x8 b, f32x4 c){
  return __builtin_amdgcn_mfma_f32_16x16x32_bf16(
      __builtin_bit_cast(bf16x8, a), __builtin_bit_cast(bf16x8, b), c, 0, 0, 0);
}
// async global->LDS, 16B per lane; LDS dest = wave-uniform base + lane*16
DI void async16(const void* g, void* l){
  __builtin_amdgcn_global_load_lds(
      (__attribute__((address_space(1))) void*)(g),
      (__attribute__((address_space(3))) void*)(l), 16, 0, 0);
}

// ---------------- fp32 -> bf16 elementwise (8/thread) ----------------
__global__ __launch_bounds__(256) void cvt_f32_bf16(const float* __restrict__ in,
                                                    unsigned short* __restrict__ out, int n8){
  const int i = blockIdx.x * 256 + threadIdx.x;
  if (i >= n8) return;
  const float4* pp = (const float4*)in + (long)i * 2;
  float4 a = pp[0], b = pp[1];
  u16x8 r;
  r[0]=f2bf(a.x); r[1]=f2bf(a.y); r[2]=f2bf(a.z); r[3]=f2bf(a.w);
  r[4]=f2bf(b.x); r[5]=f2bf(b.y); r[6]=f2bf(b.z); r[7]=f2bf(b.w);
  *(u16x8*)(out + (long)i * 8) = r;
}

// ---------------- W[K][N] fp32 -> Wt[Np][K] bf16 (zero-pad n>=N) -----
__global__ __launch_bounds__(256) void wtrans(const float* __restrict__ W,
                                              unsigned short* __restrict__ Wt,
                                              int K, int N, int Np){
  __shared__ float t[32][33];
  const int n0 = blockIdx.x * 32, k0 = blockIdx.y * 32;
  const int tid = threadIdx.x;
  const int c = tid & 31, r0 = tid >> 5;
  #pragma unroll
  for (int i = 0; i < 4; ++i){
    const int r = r0 + i * 8;
    float v = 0.f;
    if (n0 + c < N) v = W[(long)(k0 + r) * N + n0 + c];
    t[r][c] = v;
  }
  __syncthreads();
  #pragma unroll
  for (int i = 0; i < 4; ++i){
    const int r = r0 + i * 8;  // n-local
    Wt[(long)(n0 + r) * K + k0 + c] = f2bf(t[c][r]);
  }
}

// ---------------- RMSNorm: fp32 in (ld=ldx) -> bf16 out --------------
template<int COLS>
__global__ __launch_bounds__(256) void rmsnorm_k(const float* __restrict__ X, int ldx,
                                                 const float* __restrict__ g,
                                                 unsigned short* __restrict__ Y, int ldy){
  constexpr int PT = COLS / 256;
  const int row = blockIdx.x, tid = threadIdx.x;
  const float* xr = X + (long)row * ldx;
  float v[PT];
  float ss = 0.f;
  #pragma unroll
  for (int i = 0; i < PT; ++i){ v[i] = xr[tid + i * 256]; ss += v[i] * v[i]; }
  #pragma unroll
  for (int off = 32; off >= 1; off >>= 1) ss += __shfl_xor(ss, off);
  __shared__ float red[4];
  if ((tid & 63) == 0) red[tid >> 6] = ss;
  __syncthreads();
  const float tot = red[0] + red[1] + red[2] + red[3];
  const float rs = rsqrtf(tot / (float)COLS + 1e-6f);
  #pragma unroll
  for (int i = 0; i < PT; ++i)
    Y[(long)row * ldy + tid + i * 256] = f2bf(v[i] * rs * g[tid + i * 256]);
}

// ---------------- GEMM: C[M,N] = A[M,K](bf16) * Bt[N,K](bf16)^T ------
// 128x128 tile, BK=64, 4 waves (2x2), 16x16x32 MFMA, global_load_lds staging.
__global__ __launch_bounds__(256) void gemm_bt(const unsigned short* __restrict__ A,
                                               const unsigned short* __restrict__ Bt,
                                               float* __restrict__ C, int N, int K){
  __shared__ unsigned short lA[128 * 64];
  __shared__ unsigned short lB[128 * 64];
  const int tid = threadIdx.x;
  const int w = tid >> 6, lane = tid & 63, lr = lane & 15, lg = lane >> 4;
  const int wm = w >> 1, wn = w & 1;
  const long m0 = (long)blockIdx.y * 128, n0 = (long)blockIdx.x * 128;
  f32x4 acc[4][4] = {};
  const unsigned short* Ab = A + m0 * K;
  const unsigned short* Bb = Bt + n0 * K;
  for (int k0 = 0; k0 < K; k0 += 64){
    #pragma unroll
    for (int s2 = 0; s2 < 4; ++s2){
      const int c = s2 * 256 + tid;  // 16B chunk; row = c>>3 (128B rows), col = c&7
      async16(Ab + (long)(c >> 3) * K + k0 + (c & 7) * 8, &lA[(s2 * 256 + w * 64) * 8]);
      async16(Bb + (long)(c >> 3) * K + k0 + (c & 7) * 8, &lB[(s2 * 256 + w * 64) * 8]);
    }
    __syncthreads();
    u16x8 a[2][4], b[2][4];
    #pragma unroll
    for (int kk = 0; kk < 2; ++kk){
      #pragma unroll
      for (int m = 0; m < 4; ++m)
        a[kk][m] = *(const u16x8*)&lA[(wm * 64 + m * 16 + lr) * 64 + kk * 32 + lg * 8];
      #pragma unroll
      for (int n = 0; n < 4; ++n)
        b[kk][n] = *(const u16x8*)&lB[(wn * 64 + n * 16 + lr) * 64 + kk * 32 + lg * 8];
    }
    #pragma unroll
    for (int kk = 0; kk < 2; ++kk)
      #pragma unroll
      for (int m = 0; m < 4; ++m)
        #pragma unroll
        for (int n = 0; n < 4; ++n)
          acc[m][n] = mfma16(a[kk][m], b[kk][n], acc[m][n]);
    __syncthreads();
  }
  #pragma unroll
  for (int m = 0; m < 4; ++m){
    const long row = m0 + wm * 64 + m * 16 + lg * 4;
    #pragma unroll
    for (int n = 0; n < 4; ++n){
      const long col = n0 + wn * 64 + n * 16 + lr;
      #pragma unroll
      for (int r = 0; r < 4; ++r)
        C[(row + r) * N + col] = acc[m][n][r];
    }
  }
}

// ------- GEMM qb + fused RoPE/head-pack epilogue -> qf [bh][s][192] --
// N=3072, K=1536. Output scaled by QS (scale * log2e, exp2-domain attn).
__global__ __launch_bounds__(256) void gemm_qpack(const unsigned short* __restrict__ A,
                                                  const unsigned short* __restrict__ Bt,
                                                  const float* __restrict__ cosb,
                                                  const float* __restrict__ sinb,
                                                  unsigned short* __restrict__ qf, int K){
  const int N = 3072;
  __shared__ unsigned short lA[128 * 64];
  __shared__ unsigned short lB[128 * 64];
  const int tid = threadIdx.x;
  const int w = tid >> 6, lane = tid & 63, lr = lane & 15, lg = lane >> 4;
  const int wm = w >> 1, wn = w & 1;
  const long m0 = (long)blockIdx.y * 128, n0 = (long)blockIdx.x * 128;
  f32x4 acc[4][4] = {};
  const unsigned short* Ab = A + m0 * K;
  const unsigned short* Bb = Bt + n0 * K;
  for (int k0 = 0; k0 < K; k0 += 64){
    #pragma unroll
    for (int s2 = 0; s2 < 4; ++s2){
      const int c = s2 * 256 + tid;
      async16(Ab + (long)(c >> 3) * K + k0 + (c & 7) * 8, &lA[(s2 * 256 + w * 64) * 8]);
      async16(Bb + (long)(c >> 3) * K + k0 + (c & 7) * 8, &lB[(s2 * 256 + w * 64) * 8]);
    }
    __syncthreads();
    u16x8 a[2][4], b[2][4];
    #pragma unroll
    for (int kk = 0; kk < 2; ++kk){
      #pragma unroll
      for (int m = 0; m < 4; ++m)
        a[kk][m] = *(const u16x8*)&lA[(wm * 64 + m * 16 + lr) * 64 + kk * 32 + lg * 8];
      #pragma unroll
      for (int n = 0; n < 4; ++n)
        b[kk][n] = *(const u16x8*)&lB[(wn * 64 + n * 16 + lr) * 64 + kk * 32 + lg * 8];
    }
    #pragma unroll
    for (int kk = 0; kk < 2; ++kk)
      #pragma unroll
      for (int m = 0; m < 4; ++m)
        #pragma unroll
        for (int n = 0; n < 4; ++n)
          acc[m][n] = mfma16(a[kk][m], b[kk][n], acc[m][n]);
    __syncthreads();
  }
  #pragma unroll
  for (int m = 0; m < 4; ++m){
    const int rowg = (int)m0 + wm * 64 + m * 16 + lg * 4;
    #pragma unroll
    for (int n = 0; n < 4; ++n){
      const int col = (int)n0 + wn * 64 + n * 16 + lr;
      const int h = (unsigned)col / 192u;
      const int d = col - h * 192;
      #pragma unroll
      for (int r = 0; r < 4; ++r){
        const int rowi = rowg + r;           // b*S + s
        const float a = acc[m][n][r];
        const float partner = __shfl_xor(a, 1);
        float val; int dout;
        if (d < 128){ val = a; dout = d; }
        else {
          const int ii = (d - 128) >> 1;
          const float c  = cosb[(long)rowi * 64 + ii];
          const float sn = sinb[(long)rowi * 64 + ii];
          val  = (d & 1) ? (a * c + partner * sn) : (a * c - partner * sn);
          dout = 128 + ((d & 1) << 5) + ii;  // even->128+ii, odd->160+ii
        }
        const int b = rowi >> 11, s = rowi & 2047;
        qf[((long)(b * 16 + h) * S_ + s) * DQK + dout] = f2bf(val * QS);
      }
    }
  }
}

// ------- GEMM kvb + fused split epilogue: nope -> kf, v -> kvmat -----
// N=4096, K=512.
__global__ __launch_bounds__(256) void gemm_kvpack(const unsigned short* __restrict__ A,
                                                   const unsigned short* __restrict__ Bt,
                                                   unsigned short* __restrict__ kf,
                                                   unsigned short* __restrict__ kvm, int K){
  const int N = 4096;
  __shared__ unsigned short lA[128 * 64];
  __shared__ unsigned short lB[128 * 64];
  const int tid = threadIdx.x;
  const int w = tid >> 6, lane = tid & 63, lr = lane & 15, lg = lane >> 4;
  const int wm = w >> 1, wn = w & 1;
  const long m0 = (long)blockIdx.y * 128, n0 = (long)blockIdx.x * 128;
  f32x4 acc[4][4] = {};
  const unsigned short* Ab = A + m0 * K;
  const unsigned short* Bb = Bt + n0 * K;
  for (int k0 = 0; k0 < K; k0 += 64){
    #pragma unroll
    for (int s2 = 0; s2 < 4; ++s2){
      const int c = s2 * 256 + tid;
      async16(Ab + (long)(c >> 3) * K + k0 + (c & 7) * 8, &lA[(s2 * 256 + w * 64) * 8]);
      async16(Bb + (long)(c >> 3) * K + k0 + (c & 7) * 8, &lB[(s2 * 256 + w * 64) * 8]);
    }
    __syncthreads();
    u16x8 a[2][4], b[2][4];
    #pragma unroll
    for (int kk = 0; kk < 2; ++kk){
      #pragma unroll
      for (int m = 0; m < 4; ++m)
        a[kk][m] = *(const u16x8*)&lA[(wm * 64 + m * 16 + lr) * 64 + kk * 32 + lg * 8];
      #pragma unroll
      for (int n = 0; n < 4; ++n)
        b[kk][n] = *(const u16x8*)&lB[(wn * 64 + n * 16 + lr) * 64 + kk * 32 + lg * 8];
    }
    #pragma unroll
    for (int kk = 0; kk < 2; ++kk)
      #pragma unroll
      for (int m = 0; m < 4; ++m)
        #pragma unroll
        for (int n = 0; n < 4; ++n)
          acc[m][n] = mfma16(a[kk][m], b[kk][n], acc[m][n]);
    __syncthreads();
  }
  #pragma unroll
  for (int m = 0; m < 4; ++m){
    const int rowg = (int)m0 + wm * 64 + m * 16 + lg * 4;
    #pragma unroll
    for (int n = 0; n < 4; ++n){
      const int col = (int)n0 + wn * 64 + n * 16 + lr;
      const int h = col >> 8, d = col & 255;
      #pragma unroll
      for (int r = 0; r < 4; ++r){
        const int rowi = rowg + r;
        const unsigned short v = f2bf(acc[m][n][r]);
        const int b = rowi >> 11, s = rowi & 2047;
        if (d < 128) kf[((long)(b * 16 + h) * S_ + s) * DQK + d] = v;
        else         kvm[(long)rowi * 4096 + col] = v;
      }
    }
  }
}

// ------- fill kf rot cols [128,192) for all heads from ckv + RoPE ----
__global__ __launch_bounds__(256) void pack_krot(const float* __restrict__ ckv,
                                                 const float* __restrict__ cosb,
                                                 const float* __restrict__ sinb,
                                                 unsigned short* __restrict__ kf){
  const int row = blockIdx.x, tid = threadIdx.x;
  const int b = row >> 11, s = row & 2047;
  const float* cv = ckv + (long)row * CKV_LD + QR + KVR;  // rot part of merged buf
  const float* cr = cosb + (long)row * 64;
  const float* sr = sinb + (long)row * 64;
  #pragma unroll
  for (int j = 0; j < 4; ++j){
    const int o = j * 256 + tid;        // 0..1023 = h*64 + i
    const int h = o >> 6, i = o & 63, ii = i & 31;
    const float e = cv[2 * ii], od = cv[2 * ii + 1];
    const float c = cr[ii], sn = sr[ii];
    const float val = (i < 32) ? (e * c - od * sn) : (od * c + e * sn);
    kf[((long)(b * 16 + h) * S_ + s) * DQK + 128 + i] = f2bf(val);
  }
}

// ---------------- pack v: kvmat v-part -> vt [bh][128][S] (V^T) ------
__global__ __launch_bounds__(256) void pack_v(const unsigned short* __restrict__ kvm,
                                              unsigned short* __restrict__ vt){
  const int bh = blockIdx.x, s0 = blockIdx.y * 64;
  const int b = bh >> 4, h = bh & 15;
  __shared__ unsigned short t[64][130];
  #pragma unroll
  for (int it = 0; it < 32; ++it){
    const int idx = it * 256 + threadIdx.x;
    const int sl = idx >> 7, d = idx & 127;
    t[sl][d] = kvm[(long)(b * S_ + s0 + sl) * 4096 + h * 256 + 128 + d];
  }
  __syncthreads();
  #pragma unroll
  for (int it = 0; it < 32; ++it){
    const int idx = it * 256 + threadIdx.x;
    const int dr = idx >> 6, sc = idx & 63;
    vt[(long)(bh * 128 + dr) * S_ + s0 + sc] = t[sc][dr];
  }
}

// ---------------- causal flash attention (exp2 domain) ---------------
// 512 blocks (LPT: heavy qt first), 256 thr; wave w owns 32 q-rows.
// 64-key tiles; double-buffered K/V LDS (T3 minimum 2-phase: issue stage(t+1)
// before compute(t), ONE __syncthreads per tile); XOR-swizzled K/V;
// l via MFMA ones-frag; defer-max (T13).
__global__ __launch_bounds__(256) void mla_attn(const unsigned short* __restrict__ qf,
                                                const unsigned short* __restrict__ kf,
                                                const unsigned short* __restrict__ vt,
                                                unsigned short* __restrict__ ao){
  __shared__ unsigned short k_lds[2][64 * 192];   // 2x24KB, swizzled
  __shared__ unsigned short v_lds[2][128 * 64];   // 2x16KB, swizzled
  __shared__ unsigned short p_lds[4][32][72];     // per-wave P (18KB)
  const int bid = blockIdx.x;
  const int u = bid >> 5;
  const int qt = (u < 8) ? (15 - u) : (u - 8);    // LPT: heavy blocks first
  const int bh = bid & 31;
  const int b = bh >> 4, h = bh & 15;
  const int tid = threadIdx.x;
  const int w = tid >> 6, lane = tid & 63, lr = lane & 15, lg = lane >> 4;
  const int q0 = qt * 128 + w * 32;
  const unsigned short* qb = qf + (long)bh * S_ * DQK;
  const unsigned short* kb = kf + (long)bh * S_ * DQK;
  const unsigned short* vb = vt + (long)bh * 128 * S_;
  u16x8 aq[2][6];
  #pragma unroll
  for (int mi = 0; mi < 2; ++mi)
    #pragma unroll
    for (int kk = 0; kk < 6; ++kk)
      aq[mi][kk] = *(const u16x8*)&qb[(long)(q0 + mi * 16 + lr) * DQK + kk * 32 + lg * 8];
  f32x4 oacc[2][8] = {};
  f32x4 lacc[2] = {};                          // row-sum via MFMA ones-frag
  float mrun[2][4];
  #pragma unroll
  for (int mi = 0; mi < 2; ++mi)
    #pragma unroll
    for (int r = 0; r < 4; ++r) mrun[mi][r] = -1e30f;
  u16x8 onesv;
  #pragma unroll
  for (int i = 0; i < 8; ++i) onesv[i] = 0x3F80;  // bf16 1.0
  const int ktiles = (qt + 1) * 2;
  const int myktiles = ((q0 + 31) >> 6) + 1;   // tiles this wave contributes to

  auto stage = [&](int kt, int buf){
    // K tile [64][192]: source col16 pre-swizzled by row&7 (rule #21)
    #pragma unroll
    for (int s2 = 0; s2 < 6; ++s2){
      const int c = s2 * 256 + tid;
      const int row = c / 24, col = c - row * 24;
      async16(kb + (long)(kt * 64 + row) * DQK + ((col ^ (row & 7)) << 3),
              &k_lds[buf][(s2 * 256 + w * 64) * 8]);
    }
    // V^T tile [128][64]
    #pragma unroll
    for (int s2 = 0; s2 < 4; ++s2){
      const int c = s2 * 256 + tid;
      const int row = c >> 3, col = c & 7;
      async16(vb + (long)row * S_ + kt * 64 + ((col ^ (row & 7)) << 3),
              &v_lds[buf][(s2 * 256 + w * 64) * 8]);
    }
  };

  stage(0, 0);
  __syncthreads();                 // vmcnt(0) drain + barrier
  int cur = 0;
  for (int kt = 0; kt < ktiles; ++kt){
    if (kt + 1 < ktiles) stage(kt + 1, cur ^ 1);   // issue-early
    if (kt < myktiles){
      // S = Q K^T  (48 MFMAs), scores in log2 domain (Q pre-scaled)
      f32x4 sacc[2][4] = {};
      #pragma unroll
      for (int ni = 0; ni < 4; ++ni){
        const int rowk = ni * 16 + lr;
        #pragma unroll
        for (int kk = 0; kk < 6; ++kk){
          const int col16 = kk * 4 + lg;
          const u16x8 bk = *(const u16x8*)&k_lds[cur][rowk * 192 + ((col16 ^ (rowk & 7)) << 3)];
          sacc[0][ni] = mfma16(aq[0][kk], bk, sacc[0][ni]);
          sacc[1][ni] = mfma16(aq[1][kk], bk, sacc[1][ni]);
        }
      }
      // causal mask: only diagonal tiles need it (wave-uniform test)
      const int kbase = kt * 64;
      if (kbase + 63 > q0){
        #pragma unroll
        for (int mi = 0; mi < 2; ++mi)
          #pragma unroll
          for (int r = 0; r < 4; ++r){
            const int qrow = q0 + mi * 16 + lg * 4 + r;
            #pragma unroll
            for (int ni = 0; ni < 4; ++ni)
              if (kbase + ni * 16 + lr > qrow) sacc[mi][ni][r] = -1e30f;
          }
      }
      // online softmax in exp2 domain; rescale only if max grew > 8 (T13)
      #pragma unroll
      for (int mi = 0; mi < 2; ++mi)
        #pragma unroll
        for (int r = 0; r < 4; ++r){
          float tm = fmaxf(fmaxf(sacc[mi][0][r], sacc[mi][1][r]),
                           fmaxf(sacc[mi][2][r], sacc[mi][3][r]));
          tm = fmaxf(tm, __shfl_xor(tm, 1));
          tm = fmaxf(tm, __shfl_xor(tm, 2));
          tm = fmaxf(tm, __shfl_xor(tm, 4));
          tm = fmaxf(tm, __shfl_xor(tm, 8));
          if (tm > mrun[mi][r] + 8.f){
            const float sc = __builtin_exp2f(mrun[mi][r] - tm);
            mrun[mi][r] = tm;
            lacc[mi][r] *= sc;
            #pragma unroll
            for (int d = 0; d < 8; ++d) oacc[mi][d][r] *= sc;
          }
          const float m_ = mrun[mi][r];
          const int qq = mi * 16 + lg * 4 + r;
          p_lds[w][qq][lr]      = f2bf(__builtin_exp2f(sacc[mi][0][r] - m_));
          p_lds[w][qq][16 + lr] = f2bf(__builtin_exp2f(sacc[mi][1][r] - m_));
          p_lds[w][qq][32 + lr] = f2bf(__builtin_exp2f(sacc[mi][2][r] - m_));
          p_lds[w][qq][48 + lr] = f2bf(__builtin_exp2f(sacc[mi][3][r] - m_));
        }
      // O += P V ; l += P 1  (36 MFMAs)
      u16x8 pa[2][2];
      #pragma unroll
      for (int mi = 0; mi < 2; ++mi)
        #pragma unroll
        for (int kk2 = 0; kk2 < 2; ++kk2)
          pa[mi][kk2] = *(const u16x8*)&p_lds[w][mi * 16 + lr][kk2 * 32 + lg * 8];
      #pragma unroll
      for (int mi = 0; mi < 2; ++mi)
        #pragma unroll
        for (int kk2 = 0; kk2 < 2; ++kk2)
          lacc[mi] = mfma16(pa[mi][kk2], onesv, lacc[mi]);
      #pragma unroll
      for (int d = 0; d < 8; ++d){
        const int rowv = d * 16 + lr;
        #pragma unroll
        for (int kk2 = 0; kk2 < 2; ++kk2){
          const int col16 = kk2 * 4 + lg;
          const u16x8 bv = *(const u16x8*)&v_lds[cur][rowv * 64 + ((col16 ^ (rowv & 7)) << 3)];
          oacc[0][d] = mfma16(pa[0][kk2], bv, oacc[0][d]);
          oacc[1][d] = mfma16(pa[1][kk2], bv, oacc[1][d]);
        }
      }
    }
    __syncthreads();               // single per-tile drain (wait-late) + barrier
    cur ^= 1;
  }
  // epilogue: /l, store to ao[b][s][h*128+d]
  #pragma unroll
  for (int mi = 0; mi < 2; ++mi)
    #pragma unroll
    for (int r = 0; r < 4; ++r){
      const long row = q0 + mi * 16 + lg * 4 + r;
      const float inv = 1.0f / lacc[mi][r];
      #pragma unroll
      for (int d = 0; d < 8; ++d)
        ao[(long)(b * S_ + row) * 2048 + h * 128 + d * 16 + lr] = f2bf(oacc[mi][d][r] * inv);
    }
}

extern "C" void kernel_launch(void* const* d_in, const int* in_sizes, int n_in,
                              void* d_out, int out_size, void* d_ws, size_t ws_size,
                              hipStream_t stream){
  const float* hid   = (const float*)d_in[0];
  const float* w_qa  = (const float*)d_in[1];
  const float* g_qa  = (const float*)d_in[2];
  const float* w_qb  = (const float*)d_in[3];
  const float* w_kva = (const float*)d_in[4];
  const float* g_kva = (const float*)d_in[5];
  const float* w_kvb = (const float*)d_in[6];
  const float* w_o   = (const float*)d_in[7];
  const float* cosb  = (const float*)d_in[8];
  const float* sinb  = (const float*)d_in[9];
  float* out = (float*)d_out;

  char* p = (char*)d_ws;
  auto alloc = [&](size_t bytes) -> void* {
    void* r = p;
    p += (bytes + 255) & ~(size_t)255;
    return r;
  };
  unsigned short* hb      = (unsigned short*)alloc((size_t)BS * HID_ * 2);
  // merged [wqa_t ; wkva_t] rows, both K=2048 — MUST be contiguous:
  unsigned short* wqakv_t = (unsigned short*)alloc((size_t)CKV_LD * HID_ * 2);
  unsigned short* wqa_t   = wqakv_t;                       // rows 0..1535
  unsigned short* wkva_t  = wqakv_t + (size_t)QR * HID_;   // rows 1536..2175
  unsigned short* wqb_t  = (unsigned short*)alloc((size_t)3072 * QR * 2);
  unsigned short* wkvb_t = (unsigned short*)alloc((size_t)4096 * KVR * 2);
  unsigned short* wo_t   = (unsigned short*)alloc((size_t)2048 * 2048 * 2);
  float*          qakv_f = (float*)alloc((size_t)BS * CKV_LD * 4);  // qa|ckv fp32
  unsigned short* qan    = (unsigned short*)alloc((size_t)BS * QR * 2);
  unsigned short* kvn    = (unsigned short*)alloc((size_t)BS * KVR * 2);
  unsigned short* kvmat  = (unsigned short*)alloc((size_t)BS * 4096 * 2);
  unsigned short* qfb    = (unsigned short*)alloc((size_t)32 * S_ * DQK * 2);
  unsigned short* kfb    = (unsigned short*)alloc((size_t)32 * S_ * DQK * 2);
  unsigned short* vtb    = (unsigned short*)alloc((size_t)32 * 128 * S_ * 2);
  unsigned short* aob    = (unsigned short*)alloc((size_t)BS * 2048 * 2);
  (void)ws_size; (void)in_sizes; (void)n_in; (void)out_size;

  cvt_f32_bf16<<<BS * HID_ / 8 / 256, 256, 0, stream>>>(hid, hb, BS * HID_ / 8);
  wtrans<<<dim3(1536 / 32, 2048 / 32), 256, 0, stream>>>(w_qa, wqa_t, 2048, 1536, 1536);
  wtrans<<<dim3(3072 / 32, 1536 / 32), 256, 0, stream>>>(w_qb, wqb_t, 1536, 3072, 3072);
  wtrans<<<dim3(640 / 32, 2048 / 32), 256, 0, stream>>>(w_kva, wkva_t, 2048, 576, 640);
  wtrans<<<dim3(4096 / 32, 512 / 32), 256, 0, stream>>>(w_kvb, wkvb_t, 512, 4096, 4096);
  wtrans<<<dim3(2048 / 32, 2048 / 32), 256, 0, stream>>>(w_o, wo_t, 2048, 2048, 2048);

  // merged qa|kva GEMM: N=2176, K=2048
  gemm_bt<<<dim3(CKV_LD / 128, BS / 128), 256, 0, stream>>>(hb, wqakv_t, qakv_f, CKV_LD, 2048);
  rmsnorm_k<1536><<<BS, 256, 0, stream>>>(qakv_f, CKV_LD, g_qa, qan, 1536);
  rmsnorm_k<512><<<BS, 256, 0, stream>>>(qakv_f + QR, CKV_LD, g_kva, kvn, 512);

  gemm_qpack<<<dim3(3072 / 128, BS / 128), 256, 0, stream>>>(qan, wqb_t, cosb, sinb, qfb, 1536);
  gemm_kvpack<<<dim3(4096 / 128, BS / 128), 256, 0, stream>>>(kvn, wkvb_t, kfb, kvmat, 512);
  pack_krot<<<BS, 256, 0, stream>>>(qakv_f, cosb, sinb, kfb);
  pack_v<<<dim3(32, S_ / 64), 256, 0, stream>>>(kvmat, vtb);

  mla_attn<<<512, 256, 0, stream>>>(qfb, kfb, vtb, aob);

  gemm_bt<<<dim3(2048 / 128, BS / 128), 256, 0, stream>>>(aob, wo_t, out, 2048, 2048);
}

// Round 5
// 551.797 us; speedup vs baseline: 1.1556x; 1.1556x over previous
//
#include <hip/hip_runtime.h>

#define DI __device__ __forceinline__

typedef __attribute__((ext_vector_type(8))) unsigned short u16x8;
typedef __attribute__((ext_vector_type(8))) __bf16 bf16x8;
typedef __attribute__((ext_vector_type(4))) float f32x4;

constexpr int B_ = 2, S_ = 2048, H_ = 16, HID_ = 2048;
constexpr int QR = 1536, KVR = 512, DQK = 192;
constexpr int BS = B_ * S_;                 // 4096 rows
constexpr float SCALE = 0.07216878364870323f;   // 1/sqrt(192)
constexpr float QS = SCALE * 1.4426950408889634f; // fold log2e -> exp2 domain
constexpr int CKV_LD = 2176;                // merged qa|kva fp32 buffer ld

// HW bf16 convert (RTNE), 1 instr
DI unsigned short f2bf(float x){
  unsigned r;
  asm("v_cvt_pk_bf16_f32 %0, %1, %2" : "=v"(r) : "v"(x), "v"(x));
  return (unsigned short)r;
}
DI float bf2f(unsigned short h){
  return __builtin_bit_cast(float, ((unsigned)h) << 16);
}
DI f32x4 mfma16(u16x8 a, u16x8 b, f32x4 c){
  return __builtin_amdgcn_mfma_f32_16x16x32_bf16(
      __builtin_bit_cast(bf16x8, a), __builtin_bit_cast(bf16x8, b), c, 0, 0, 0);
}
// async global->LDS, 16B per lane; LDS dest = wave-uniform base + lane*16
DI void async16(const void* g, void* l){
  __builtin_amdgcn_global_load_lds(
      (__attribute__((address_space(1))) void*)(g),
      (__attribute__((address_space(3))) void*)(l), 16, 0, 0);
}

// ---------------- fp32 -> bf16 elementwise (8/thread) ----------------
__global__ __launch_bounds__(256) void cvt_f32_bf16(const float* __restrict__ in,
                                                    unsigned short* __restrict__ out, int n8){
  const int i = blockIdx.x * 256 + threadIdx.x;
  if (i >= n8) return;
  const float4* pp = (const float4*)in + (long)i * 2;
  float4 a = pp[0], b = pp[1];
  u16x8 r;
  r[0]=f2bf(a.x); r[1]=f2bf(a.y); r[2]=f2bf(a.z); r[3]=f2bf(a.w);
  r[4]=f2bf(b.x); r[5]=f2bf(b.y); r[6]=f2bf(b.z); r[7]=f2bf(b.w);
  *(u16x8*)(out + (long)i * 8) = r;
}

// ---------------- W[K][N] fp32 -> Wt[Np][K] bf16 (zero-pad n>=N) -----
__global__ __launch_bounds__(256) void wtrans(const float* __restrict__ W,
                                              unsigned short* __restrict__ Wt,
                                              int K, int N, int Np){
  __shared__ float t[32][33];
  const int n0 = blockIdx.x * 32, k0 = blockIdx.y * 32;
  const int tid = threadIdx.x;
  const int c = tid & 31, r0 = tid >> 5;
  #pragma unroll
  for (int i = 0; i < 4; ++i){
    const int r = r0 + i * 8;
    float v = 0.f;
    if (n0 + c < N) v = W[(long)(k0 + r) * N + n0 + c];
    t[r][c] = v;
  }
  __syncthreads();
  #pragma unroll
  for (int i = 0; i < 4; ++i){
    const int r = r0 + i * 8;  // n-local
    Wt[(long)(n0 + r) * K + k0 + c] = f2bf(t[c][r]);
  }
}

// ---------------- RMSNorm: fp32 in (ld=ldx) -> bf16 out --------------
template<int COLS>
__global__ __launch_bounds__(256) void rmsnorm_k(const float* __restrict__ X, int ldx,
                                                 const float* __restrict__ g,
                                                 unsigned short* __restrict__ Y, int ldy){
  constexpr int PT = COLS / 256;
  const int row = blockIdx.x, tid = threadIdx.x;
  const float* xr = X + (long)row * ldx;
  float v[PT];
  float ss = 0.f;
  #pragma unroll
  for (int i = 0; i < PT; ++i){ v[i] = xr[tid + i * 256]; ss += v[i] * v[i]; }
  #pragma unroll
  for (int off = 32; off >= 1; off >>= 1) ss += __shfl_xor(ss, off);
  __shared__ float red[4];
  if ((tid & 63) == 0) red[tid >> 6] = ss;
  __syncthreads();
  const float tot = red[0] + red[1] + red[2] + red[3];
  const float rs = rsqrtf(tot / (float)COLS + 1e-6f);
  #pragma unroll
  for (int i = 0; i < PT; ++i)
    Y[(long)row * ldy + tid + i * 256] = f2bf(v[i] * rs * g[tid + i * 256]);
}

// ---------------- GEMM: C[M,N] = A[M,K](bf16) * Bt[N,K](bf16)^T ------
// 128x128 tile, BK=64, 4 waves (2x2), 16x16x32 MFMA, global_load_lds staging.
__global__ __launch_bounds__(256) void gemm_bt(const unsigned short* __restrict__ A,
                                               const unsigned short* __restrict__ Bt,
                                               float* __restrict__ C, int N, int K){
  __shared__ unsigned short lA[128 * 64];
  __shared__ unsigned short lB[128 * 64];
  const int tid = threadIdx.x;
  const int w = tid >> 6, lane = tid & 63, lr = lane & 15, lg = lane >> 4;
  const int wm = w >> 1, wn = w & 1;
  const long m0 = (long)blockIdx.y * 128, n0 = (long)blockIdx.x * 128;
  f32x4 acc[4][4] = {};
  const unsigned short* Ab = A + m0 * K;
  const unsigned short* Bb = Bt + n0 * K;
  for (int k0 = 0; k0 < K; k0 += 64){
    #pragma unroll
    for (int s2 = 0; s2 < 4; ++s2){
      const int c = s2 * 256 + tid;  // 16B chunk; row = c>>3 (128B rows), col = c&7
      async16(Ab + (long)(c >> 3) * K + k0 + (c & 7) * 8, &lA[(s2 * 256 + w * 64) * 8]);
      async16(Bb + (long)(c >> 3) * K + k0 + (c & 7) * 8, &lB[(s2 * 256 + w * 64) * 8]);
    }
    __syncthreads();
    u16x8 a[2][4], b[2][4];
    #pragma unroll
    for (int kk = 0; kk < 2; ++kk){
      #pragma unroll
      for (int m = 0; m < 4; ++m)
        a[kk][m] = *(const u16x8*)&lA[(wm * 64 + m * 16 + lr) * 64 + kk * 32 + lg * 8];
      #pragma unroll
      for (int n = 0; n < 4; ++n)
        b[kk][n] = *(const u16x8*)&lB[(wn * 64 + n * 16 + lr) * 64 + kk * 32 + lg * 8];
    }
    #pragma unroll
    for (int kk = 0; kk < 2; ++kk)
      #pragma unroll
      for (int m = 0; m < 4; ++m)
        #pragma unroll
        for (int n = 0; n < 4; ++n)
          acc[m][n] = mfma16(a[kk][m], b[kk][n], acc[m][n]);
    __syncthreads();
  }
  #pragma unroll
  for (int m = 0; m < 4; ++m){
    const long row = m0 + wm * 64 + m * 16 + lg * 4;
    #pragma unroll
    for (int n = 0; n < 4; ++n){
      const long col = n0 + wn * 64 + n * 16 + lr;
      #pragma unroll
      for (int r = 0; r < 4; ++r)
        C[(row + r) * N + col] = acc[m][n][r];
    }
  }
}

// ------- GEMM qb + fused RoPE/head-pack epilogue -> qf [bh][s][192] --
// N=3072, K=1536. Output scaled by QS (scale * log2e, exp2-domain attn).
__global__ __launch_bounds__(256) void gemm_qpack(const unsigned short* __restrict__ A,
                                                  const unsigned short* __restrict__ Bt,
                                                  const float* __restrict__ cosb,
                                                  const float* __restrict__ sinb,
                                                  unsigned short* __restrict__ qf, int K){
  const int N = 3072;
  __shared__ unsigned short lA[128 * 64];
  __shared__ unsigned short lB[128 * 64];
  const int tid = threadIdx.x;
  const int w = tid >> 6, lane = tid & 63, lr = lane & 15, lg = lane >> 4;
  const int wm = w >> 1, wn = w & 1;
  const long m0 = (long)blockIdx.y * 128, n0 = (long)blockIdx.x * 128;
  f32x4 acc[4][4] = {};
  const unsigned short* Ab = A + m0 * K;
  const unsigned short* Bb = Bt + n0 * K;
  for (int k0 = 0; k0 < K; k0 += 64){
    #pragma unroll
    for (int s2 = 0; s2 < 4; ++s2){
      const int c = s2 * 256 + tid;
      async16(Ab + (long)(c >> 3) * K + k0 + (c & 7) * 8, &lA[(s2 * 256 + w * 64) * 8]);
      async16(Bb + (long)(c >> 3) * K + k0 + (c & 7) * 8, &lB[(s2 * 256 + w * 64) * 8]);
    }
    __syncthreads();
    u16x8 a[2][4], b[2][4];
    #pragma unroll
    for (int kk = 0; kk < 2; ++kk){
      #pragma unroll
      for (int m = 0; m < 4; ++m)
        a[kk][m] = *(const u16x8*)&lA[(wm * 64 + m * 16 + lr) * 64 + kk * 32 + lg * 8];
      #pragma unroll
      for (int n = 0; n < 4; ++n)
        b[kk][n] = *(const u16x8*)&lB[(wn * 64 + n * 16 + lr) * 64 + kk * 32 + lg * 8];
    }
    #pragma unroll
    for (int kk = 0; kk < 2; ++kk)
      #pragma unroll
      for (int m = 0; m < 4; ++m)
        #pragma unroll
        for (int n = 0; n < 4; ++n)
          acc[m][n] = mfma16(a[kk][m], b[kk][n], acc[m][n]);
    __syncthreads();
  }
  #pragma unroll
  for (int m = 0; m < 4; ++m){
    const int rowg = (int)m0 + wm * 64 + m * 16 + lg * 4;
    #pragma unroll
    for (int n = 0; n < 4; ++n){
      const int col = (int)n0 + wn * 64 + n * 16 + lr;
      const int h = (unsigned)col / 192u;
      const int d = col - h * 192;
      #pragma unroll
      for (int r = 0; r < 4; ++r){
        const int rowi = rowg + r;           // b*S + s
        const float a = acc[m][n][r];
        const float partner = __shfl_xor(a, 1);
        float val; int dout;
        if (d < 128){ val = a; dout = d; }
        else {
          const int ii = (d - 128) >> 1;
          const float c  = cosb[(long)rowi * 64 + ii];
          const float sn = sinb[(long)rowi * 64 + ii];
          val  = (d & 1) ? (a * c + partner * sn) : (a * c - partner * sn);
          dout = 128 + ((d & 1) << 5) + ii;  // even->128+ii, odd->160+ii
        }
        const int b = rowi >> 11, s = rowi & 2047;
        qf[((long)(b * 16 + h) * S_ + s) * DQK + dout] = f2bf(val * QS);
      }
    }
  }
}

// ------- GEMM kvb + fused split epilogue: nope -> kf, v -> kvmat -----
// N=4096, K=512.
__global__ __launch_bounds__(256) void gemm_kvpack(const unsigned short* __restrict__ A,
                                                   const unsigned short* __restrict__ Bt,
                                                   unsigned short* __restrict__ kf,
                                                   unsigned short* __restrict__ kvm, int K){
  const int N = 4096;
  __shared__ unsigned short lA[128 * 64];
  __shared__ unsigned short lB[128 * 64];
  const int tid = threadIdx.x;
  const int w = tid >> 6, lane = tid & 63, lr = lane & 15, lg = lane >> 4;
  const int wm = w >> 1, wn = w & 1;
  const long m0 = (long)blockIdx.y * 128, n0 = (long)blockIdx.x * 128;
  f32x4 acc[4][4] = {};
  const unsigned short* Ab = A + m0 * K;
  const unsigned short* Bb = Bt + n0 * K;
  for (int k0 = 0; k0 < K; k0 += 64){
    #pragma unroll
    for (int s2 = 0; s2 < 4; ++s2){
      const int c = s2 * 256 + tid;
      async16(Ab + (long)(c >> 3) * K + k0 + (c & 7) * 8, &lA[(s2 * 256 + w * 64) * 8]);
      async16(Bb + (long)(c >> 3) * K + k0 + (c & 7) * 8, &lB[(s2 * 256 + w * 64) * 8]);
    }
    __syncthreads();
    u16x8 a[2][4], b[2][4];
    #pragma unroll
    for (int kk = 0; kk < 2; ++kk){
      #pragma unroll
      for (int m = 0; m < 4; ++m)
        a[kk][m] = *(const u16x8*)&lA[(wm * 64 + m * 16 + lr) * 64 + kk * 32 + lg * 8];
      #pragma unroll
      for (int n = 0; n < 4; ++n)
        b[kk][n] = *(const u16x8*)&lB[(wn * 64 + n * 16 + lr) * 64 + kk * 32 + lg * 8];
    }
    #pragma unroll
    for (int kk = 0; kk < 2; ++kk)
      #pragma unroll
      for (int m = 0; m < 4; ++m)
        #pragma unroll
        for (int n = 0; n < 4; ++n)
          acc[m][n] = mfma16(a[kk][m], b[kk][n], acc[m][n]);
    __syncthreads();
  }
  #pragma unroll
  for (int m = 0; m < 4; ++m){
    const int rowg = (int)m0 + wm * 64 + m * 16 + lg * 4;
    #pragma unroll
    for (int n = 0; n < 4; ++n){
      const int col = (int)n0 + wn * 64 + n * 16 + lr;
      const int h = col >> 8, d = col & 255;
      #pragma unroll
      for (int r = 0; r < 4; ++r){
        const int rowi = rowg + r;
        const unsigned short v = f2bf(acc[m][n][r]);
        const int b = rowi >> 11, s = rowi & 2047;
        if (d < 128) kf[((long)(b * 16 + h) * S_ + s) * DQK + d] = v;
        else         kvm[(long)rowi * 4096 + col] = v;
      }
    }
  }
}

// ------- fill kf rot cols [128,192) for all heads from ckv + RoPE ----
__global__ __launch_bounds__(256) void pack_krot(const float* __restrict__ ckv,
                                                 const float* __restrict__ cosb,
                                                 const float* __restrict__ sinb,
                                                 unsigned short* __restrict__ kf){
  const int row = blockIdx.x, tid = threadIdx.x;
  const int b = row >> 11, s = row & 2047;
  const float* cv = ckv + (long)row * CKV_LD + QR + KVR;  // rot part of merged buf
  const float* cr = cosb + (long)row * 64;
  const float* sr = sinb + (long)row * 64;
  #pragma unroll
  for (int j = 0; j < 4; ++j){
    const int o = j * 256 + tid;        // 0..1023 = h*64 + i
    const int h = o >> 6, i = o & 63, ii = i & 31;
    const float e = cv[2 * ii], od = cv[2 * ii + 1];
    const float c = cr[ii], sn = sr[ii];
    const float val = (i < 32) ? (e * c - od * sn) : (od * c + e * sn);
    kf[((long)(b * 16 + h) * S_ + s) * DQK + 128 + i] = f2bf(val);
  }
}

// ---------------- pack v: kvmat v-part -> vt [bh][128][S] (V^T) ------
__global__ __launch_bounds__(256) void pack_v(const unsigned short* __restrict__ kvm,
                                              unsigned short* __restrict__ vt){
  const int bh = blockIdx.x, s0 = blockIdx.y * 64;
  const int b = bh >> 4, h = bh & 15;
  __shared__ unsigned short t[64][130];
  #pragma unroll
  for (int it = 0; it < 32; ++it){
    const int idx = it * 256 + threadIdx.x;
    const int sl = idx >> 7, d = idx & 127;
    t[sl][d] = kvm[(long)(b * S_ + s0 + sl) * 4096 + h * 256 + 128 + d];
  }
  __syncthreads();
  #pragma unroll
  for (int it = 0; it < 32; ++it){
    const int idx = it * 256 + threadIdx.x;
    const int dr = idx >> 6, sc = idx & 63;
    vt[(long)(bh * 128 + dr) * S_ + s0 + sc] = t[sc][dr];
  }
}

// ---------------- causal flash attention (exp2 domain) ---------------
// Grid 1024 = 32 qtiles x 32 bh, heavy qtiles first; 256 thr; wave w owns
// 16 q-rows (QBLK=64). 64-key tiles, single-buffer stage->sync->compute->sync.
// K/V LDS XOR-swizzled; l via MFMA ones-frag; defer-max (T13); exp2 domain.
// LDS 49KB -> 3 blocks/CU resident.
__global__ __launch_bounds__(256) void mla_attn(const unsigned short* __restrict__ qf,
                                                const unsigned short* __restrict__ kf,
                                                const unsigned short* __restrict__ vt,
                                                unsigned short* __restrict__ ao){
  __shared__ unsigned short k_lds[64 * 192];   // [key][192] swizzled (24KB)
  __shared__ unsigned short v_lds[128 * 64];   // [d][key] swizzled (16KB)
  __shared__ unsigned short p_lds[4][16][72];  // per-wave P [q16][64key] (9KB)
  const int bid = blockIdx.x;
  const int u = bid >> 5;
  const int qt = 31 - u;                       // heavy first (LPT)
  const int bh = bid & 31;
  const int b = bh >> 4, h = bh & 15;
  const int tid = threadIdx.x;
  const int w = tid >> 6, lane = tid & 63, lr = lane & 15, lg = lane >> 4;
  const int q0 = qt * 64 + w * 16;
  const unsigned short* qb = qf + (long)bh * S_ * DQK;
  const unsigned short* kb = kf + (long)bh * S_ * DQK;
  const unsigned short* vb = vt + (long)bh * 128 * S_;
  u16x8 aq[6];
  #pragma unroll
  for (int kk = 0; kk < 6; ++kk)
    aq[kk] = *(const u16x8*)&qb[(long)(q0 + lr) * DQK + kk * 32 + lg * 8];
  f32x4 oacc[8] = {};
  f32x4 lacc = {};                             // row-sum via MFMA ones-frag
  float mrun[4] = {-1e30f, -1e30f, -1e30f, -1e30f};
  u16x8 onesv;
  #pragma unroll
  for (int i = 0; i < 8; ++i) onesv[i] = 0x3F80;  // bf16 1.0
  const int ktiles = qt + 1;
  for (int kt = 0; kt < ktiles; ++kt){
    // stage K tile [64][192]: source col16 pre-swizzled by row&7 (rule #21)
    #pragma unroll
    for (int s2 = 0; s2 < 6; ++s2){
      const int c = s2 * 256 + tid;
      const int row = c / 24, col = c - row * 24;
      async16(kb + (long)(kt * 64 + row) * DQK + ((col ^ (row & 7)) << 3),
              &k_lds[(s2 * 256 + w * 64) * 8]);
    }
    // stage V^T tile [128][64]
    #pragma unroll
    for (int s2 = 0; s2 < 4; ++s2){
      const int c = s2 * 256 + tid;
      const int row = c >> 3, col = c & 7;
      async16(vb + (long)row * S_ + kt * 64 + ((col ^ (row & 7)) << 3),
              &v_lds[(s2 * 256 + w * 64) * 8]);
    }
    __syncthreads();
    // S = Q K^T  (24 MFMAs), scores in log2 domain (Q pre-scaled by QS)
    f32x4 sacc[4] = {};
    #pragma unroll
    for (int ni = 0; ni < 4; ++ni){
      const int rowk = ni * 16 + lr;
      #pragma unroll
      for (int kk = 0; kk < 6; ++kk){
        const int col16 = kk * 4 + lg;
        const u16x8 bk = *(const u16x8*)&k_lds[rowk * 192 + ((col16 ^ (rowk & 7)) << 3)];
        sacc[ni] = mfma16(aq[kk], bk, sacc[ni]);
      }
    }
    // causal mask: only the diagonal tile (kt == qt), wave-uniform test
    if (kt == qt){
      #pragma unroll
      for (int r = 0; r < 4; ++r){
        const int qloc = w * 16 + lg * 4 + r;   // q-row rel. to kbase
        #pragma unroll
        for (int ni = 0; ni < 4; ++ni)
          if (ni * 16 + lr > qloc) sacc[ni][r] = -1e30f;
      }
    }
    // online softmax (16-lane row groups); rescale only if max grew >8 (T13)
    #pragma unroll
    for (int r = 0; r < 4; ++r){
      float tm = fmaxf(fmaxf(sacc[0][r], sacc[1][r]),
                       fmaxf(sacc[2][r], sacc[3][r]));
      tm = fmaxf(tm, __shfl_xor(tm, 1));
      tm = fmaxf(tm, __shfl_xor(tm, 2));
      tm = fmaxf(tm, __shfl_xor(tm, 4));
      tm = fmaxf(tm, __shfl_xor(tm, 8));
      if (tm > mrun[r] + 8.f){
        const float sc = __builtin_exp2f(mrun[r] - tm);
        mrun[r] = tm;
        lacc[r] *= sc;
        #pragma unroll
        for (int d = 0; d < 8; ++d) oacc[d][r] *= sc;
      }
      const float m_ = mrun[r];
      const int qq = lg * 4 + r;
      p_lds[w][qq][lr]      = f2bf(__builtin_exp2f(sacc[0][r] - m_));
      p_lds[w][qq][16 + lr] = f2bf(__builtin_exp2f(sacc[1][r] - m_));
      p_lds[w][qq][32 + lr] = f2bf(__builtin_exp2f(sacc[2][r] - m_));
      p_lds[w][qq][48 + lr] = f2bf(__builtin_exp2f(sacc[3][r] - m_));
    }
    // O += P V ; l += P 1  (18 MFMAs)
    u16x8 pa[2];
    #pragma unroll
    for (int kk2 = 0; kk2 < 2; ++kk2)
      pa[kk2] = *(const u16x8*)&p_lds[w][lr][kk2 * 32 + lg * 8];
    #pragma unroll
    for (int kk2 = 0; kk2 < 2; ++kk2)
      lacc = mfma16(pa[kk2], onesv, lacc);
    #pragma unroll
    for (int d = 0; d < 8; ++d){
      const int rowv = d * 16 + lr;
      #pragma unroll
      for (int kk2 = 0; kk2 < 2; ++kk2){
        const int col16 = kk2 * 4 + lg;
        const u16x8 bv = *(const u16x8*)&v_lds[rowv * 64 + ((col16 ^ (rowv & 7)) << 3)];
        oacc[d] = mfma16(pa[kk2], bv, oacc[d]);
      }
    }
    __syncthreads();
  }
  // epilogue: /l, store to ao[b][s][h*128+d]
  #pragma unroll
  for (int r = 0; r < 4; ++r){
    const long row = q0 + lg * 4 + r;
    const float inv = 1.0f / lacc[r];
    #pragma unroll
    for (int d = 0; d < 8; ++d)
      ao[(long)(b * S_ + row) * 2048 + h * 128 + d * 16 + lr] = f2bf(oacc[d][r] * inv);
  }
}

extern "C" void kernel_launch(void* const* d_in, const int* in_sizes, int n_in,
                              void* d_out, int out_size, void* d_ws, size_t ws_size,
                              hipStream_t stream){
  const float* hid   = (const float*)d_in[0];
  const float* w_qa  = (const float*)d_in[1];
  const float* g_qa  = (const float*)d_in[2];
  const float* w_qb  = (const float*)d_in[3];
  const float* w_kva = (const float*)d_in[4];
  const float* g_kva = (const float*)d_in[5];
  const float* w_kvb = (const float*)d_in[6];
  const float* w_o   = (const float*)d_in[7];
  const float* cosb  = (const float*)d_in[8];
  const float* sinb  = (const float*)d_in[9];
  float* out = (float*)d_out;

  char* p = (char*)d_ws;
  auto alloc = [&](size_t bytes) -> void* {
    void* r = p;
    p += (bytes + 255) & ~(size_t)255;
    return r;
  };
  unsigned short* hb      = (unsigned short*)alloc((size_t)BS * HID_ * 2);
  // merged [wqa_t ; wkva_t] rows, both K=2048 — MUST be contiguous:
  unsigned short* wqakv_t = (unsigned short*)alloc((size_t)CKV_LD * HID_ * 2);
  unsigned short* wqa_t   = wqakv_t;                       // rows 0..1535
  unsigned short* wkva_t  = wqakv_t + (size_t)QR * HID_;   // rows 1536..2175
  unsigned short* wqb_t  = (unsigned short*)alloc((size_t)3072 * QR * 2);
  unsigned short* wkvb_t = (unsigned short*)alloc((size_t)4096 * KVR * 2);
  unsigned short* wo_t   = (unsigned short*)alloc((size_t)2048 * 2048 * 2);
  float*          qakv_f = (float*)alloc((size_t)BS * CKV_LD * 4);  // qa|ckv fp32
  unsigned short* qan    = (unsigned short*)alloc((size_t)BS * QR * 2);
  unsigned short* kvn    = (unsigned short*)alloc((size_t)BS * KVR * 2);
  unsigned short* kvmat  = (unsigned short*)alloc((size_t)BS * 4096 * 2);
  unsigned short* qfb    = (unsigned short*)alloc((size_t)32 * S_ * DQK * 2);
  unsigned short* kfb    = (unsigned short*)alloc((size_t)32 * S_ * DQK * 2);
  unsigned short* vtb    = (unsigned short*)alloc((size_t)32 * 128 * S_ * 2);
  unsigned short* aob    = (unsigned short*)alloc((size_t)BS * 2048 * 2);
  (void)ws_size; (void)in_sizes; (void)n_in; (void)out_size;

  cvt_f32_bf16<<<BS * HID_ / 8 / 256, 256, 0, stream>>>(hid, hb, BS * HID_ / 8);
  wtrans<<<dim3(1536 / 32, 2048 / 32), 256, 0, stream>>>(w_qa, wqa_t, 2048, 1536, 1536);
  wtrans<<<dim3(3072 / 32, 1536 / 32), 256, 0, stream>>>(w_qb, wqb_t, 1536, 3072, 3072);
  wtrans<<<dim3(640 / 32, 2048 / 32), 256, 0, stream>>>(w_kva, wkva_t, 2048, 576, 640);
  wtrans<<<dim3(4096 / 32, 512 / 32), 256, 0, stream>>>(w_kvb, wkvb_t, 512, 4096, 4096);
  wtrans<<<dim3(2048 / 32, 2048 / 32), 256, 0, stream>>>(w_o, wo_t, 2048, 2048, 2048);

  // merged qa|kva GEMM: N=2176, K=2048
  gemm_bt<<<dim3(CKV_LD / 128, BS / 128), 256, 0, stream>>>(hb, wqakv_t, qakv_f, CKV_LD, 2048);
  rmsnorm_k<1536><<<BS, 256, 0, stream>>>(qakv_f, CKV_LD, g_qa, qan, 1536);
  rmsnorm_k<512><<<BS, 256, 0, stream>>>(qakv_f + QR, CKV_LD, g_kva, kvn, 512);

  gemm_qpack<<<dim3(3072 / 128, BS / 128), 256, 0, stream>>>(qan, wqb_t, cosb, sinb, qfb, 1536);
  gemm_kvpack<<<dim3(4096 / 128, BS / 128), 256, 0, stream>>>(kvn, wkvb_t, kfb, kvmat, 512);
  pack_krot<<<BS, 256, 0, stream>>>(qakv_f, cosb, sinb, kfb);
  pack_v<<<dim3(32, S_ / 64), 256, 0, stream>>>(kvmat, vtb);

  mla_attn<<<1024, 256, 0, stream>>>(qfb, kfb, vtb, aob);

  gemm_bt<<<dim3(2048 / 128, BS / 128), 256, 0, stream>>>(aob, wo_t, out, 2048, 2048);
}